// Round 8
// baseline (20520.093 us; speedup 1.0000x reference)
//
#include <hip/hip_runtime.h>

// TdLstm: twin BasicLSTM (i,j,f,o; forget_bias=1) + final dense.
// Persistent kernel, 256 WGs, LDS ~70.5KB (<=72KB proven-safe residency size).
// W^T in VGPRs (52 frags/wave, M-split). Runtime XCD handshake constructs
// 16-WG exchange groups from co-located WGs; h exchange + step flags live in
// the XCD-local L2 (plain stores + sc0 loads). Producers ALWAYS bump the L3
// group counter; uni consumers use bounded flag-poll with L3-counter fallback
// -> no verdict mixture or visibility failure can deadlock.
// ws: [0,8192) handshake/counters/flags (memset), [8192,+1MiB) h ping-pong,
// then 1MiB final h (f32).

using bf16x8 = __attribute__((ext_vector_type(8))) __bf16;
using f32x4  = __attribute__((ext_vector_type(4))) float;
using u32x4  = __attribute__((ext_vector_type(4))) unsigned int;
typedef unsigned short u16;
typedef unsigned long long u64;

#define NT 128
#define ROWB 1664                                  // 832 k-elems * 2B per B-row
#define SWZ(row, off) ((off) ^ (((row) & 7) << 4)) // bank swizzle, 16B granules

#define LGKM0  asm volatile("s_waitcnt lgkmcnt(0)" ::: "memory")
#define VM0    asm volatile("s_waitcnt vmcnt(0)" ::: "memory")
#define BAR()  __builtin_amdgcn_s_barrier()
#define SCHED0 __builtin_amdgcn_sched_barrier(0)

__device__ __forceinline__ u16 f2bf(float f) {
  union { float f; unsigned u; } v; v.f = f;
  unsigned r = v.u + 0x7fffu + ((v.u >> 16) & 1u);
  return (u16)(r >> 16);
}
__device__ __forceinline__ float sigf(float x) { return 1.f / (1.f + __expf(-x)); }
__device__ __forceinline__ float tanhf_(float x) { return 2.f / (1.f + __expf(-2.f * x)) - 1.f; }

// static-index store into A-fragment array (avoid scratch, rule #20)
__device__ __forceinline__ void setA26(bf16x8 (&A)[26], int kt, bf16x8 v) {
  switch (kt) {
    case 0:A[0]=v;break;  case 1:A[1]=v;break;  case 2:A[2]=v;break;
    case 3:A[3]=v;break;  case 4:A[4]=v;break;  case 5:A[5]=v;break;
    case 6:A[6]=v;break;  case 7:A[7]=v;break;  case 8:A[8]=v;break;
    case 9:A[9]=v;break;  case 10:A[10]=v;break; case 11:A[11]=v;break;
    case 12:A[12]=v;break; case 13:A[13]=v;break; case 14:A[14]=v;break;
    case 15:A[15]=v;break; case 16:A[16]=v;break; case 17:A[17]=v;break;
    case 18:A[18]=v;break; case 19:A[19]=v;break; case 20:A[20]=v;break;
    case 21:A[21]=v;break; case 22:A[22]=v;break; case 23:A[23]=v;break;
    case 24:A[24]=v;break; case 25:A[25]=v;break;
  }
}

__global__ __launch_bounds__(256, 1) void lstm_persist(
    const int* __restrict__ lids, const int* __restrict__ rids,
    const int* __restrict__ llen, const int* __restrict__ rlen,
    const float* __restrict__ emb,
    const float* __restrict__ Wl, const float* __restrict__ bl,
    const float* __restrict__ Wr, const float* __restrict__ br,
    u64* __restrict__ hbuf,      // [2 lstm][2 buf][256][128] u64 (bf16 x4)
    float* __restrict__ hfin,    // [2 lstm][256][512] f32
    unsigned int* __restrict__ bar) // 8KB: [0..511] grp ctrs, [512] grid, [576..831] xcd tab, [1024..1535] flags
{
  __shared__ __align__(16) unsigned char sB[32 * ROWB]; // 52 KiB (also W scratch)
  __shared__ __align__(8)  u16 sH[32][36];              // h-out staging
  __shared__ int sI[4096];                              // xcd table / ids (16 KiB)
  __shared__ int sCnt[8];

  const int tid = threadIdx.x;
  const int w = tid >> 6, l = tid & 63;
  const int bid = blockIdx.x;

  // ---- handshake: publish XCD, grid barrier (L3, proven), read placement ----
  unsigned myxcd;
  asm volatile("s_getreg_b32 %0, hwreg(20, 0, 32)" : "=s"(myxcd));  // HW_REG_XCC_ID
  myxcd &= 7u;
  if (tid == 0)
    __hip_atomic_store(&bar[576 + bid], myxcd, __ATOMIC_RELAXED, __HIP_MEMORY_SCOPE_AGENT);
  VM0;
  if (tid == 0) {
    __hip_atomic_fetch_add(&bar[512], 1u, __ATOMIC_RELAXED, __HIP_MEMORY_SCOPE_AGENT);
    while (__hip_atomic_load(&bar[512], __ATOMIC_RELAXED, __HIP_MEMORY_SCOPE_AGENT) < 256u)
      __builtin_amdgcn_s_sleep(8);
  }
  __syncthreads();
  if (tid < 256)
    sI[tid] = (int)__hip_atomic_load(&bar[576 + tid], __ATOMIC_RELAXED, __HIP_MEMORY_SCOPE_AGENT);
  __syncthreads();
  if (tid < 8) {
    int c = 0;
    for (int i = 0; i < 256; ++i) c += (sI[i] == tid);
    sCnt[tid] = c;
  }
  __syncthreads();
  bool uni = true;
  #pragma unroll
  for (int x = 0; x < 8; ++x) uni &= (sCnt[x] == 32);
  int rank = 0;
  for (int i = 0; i < bid; ++i) rank += (sI[i] == (int)myxcd);
  __syncthreads();

  // ---- role assignment (bijective either way -> placement-independent output)
  int grp, ct;
  if (uni) { grp = (int)myxcd * 2 + (rank >> 4); ct = rank & 15; }
  else     { int xcd = bid & 7, idxq = bid >> 3; grp = xcd * 2 + (idxq >> 4); ct = idxq & 15; }
  const int lstm = grp >> 3, bt = grp & 7;
  const int b0 = bt * 32, u0 = ct * 32;

  const int*   ids  = lstm ? rids : lids;
  const int*   lenp = lstm ? rlen : llen;
  const float* W    = lstm ? Wr : Wl;
  const float* bv   = lstm ? br : bl;
  unsigned int* const blp   = bar + grp * 32;     // L3 counter (always bumped)
  unsigned int* const flagb = bar + 1024;         // flags[grp][parity][ct]

  // ---- one-time: build W^T A-fragments (M-split: wave w owns mf=2w,2w+1) ----
  bf16x8 A0[26], A1[26];
  {
    float* sW = (float*)sB;                // [4 g][64 r][32 c] = 32 KiB scratch
    for (int kc = 0; kc < 13; ++kc) {
      for (int i = 0; i < 32; ++i) {
        int id2 = tid + i * 256;
        int c = id2 & 31, r = (id2 >> 5) & 63, g = id2 >> 11;
        int kk = kc * 64 + r;
        float v = 0.f;
        if (kk < 300)       v = W[kk * 2048 + g * 512 + u0 + c];
        else if (kk >= 320) v = W[(kk - 20) * 2048 + g * 512 + u0 + c];
        sW[(g * 64 + r) * 32 + c] = v;
      }
      __syncthreads();
      #pragma unroll
      for (int kt2 = 0; kt2 < 2; ++kt2) {
        int kt = kc * 2 + kt2;
        #pragma unroll
        for (int mf2 = 0; mf2 < 2; ++mf2) {
          int mf = w * 2 + mf2;
          int rho = mf * 16 + (l & 15);    // col map rho = du*4 + g
          int du = rho >> 2, g = rho & 3;
          union { u16 s[8]; bf16x8 v; } tmp;
          #pragma unroll
          for (int j = 0; j < 8; ++j) {
            int kr = kt2 * 32 + ((l >> 4) << 3) + j;
            tmp.s[j] = f2bf(sW[(g * 64 + kr) * 32 + du]);
          }
          if (mf2 == 0) setA26(A0, kt, tmp.v); else setA26(A1, kt, tmp.v);
        }
      }
      __syncthreads();
    }
  }

  // zero-pad x region k in [300,320)
  if (tid < 160) {
    int row = tid / 5, c5 = tid - (tid / 5) * 5;
    *(u64*)(sB + row * ROWB + SWZ(row, 600 + c5 * 8)) = 0ULL;
  }
  // preload ids for this b-tile
  {
    const int* src = ids + b0 * NT;
    #pragma unroll
    for (int i = 0; i < 4; ++i)
      *(int4*)&sI[(tid + i * 256) * 4] = *(const int4*)&src[(tid + i * 256) * 4];
  }

  int ldsoff[10], sirow[10], foff[10];
  #pragma unroll
  for (int i = 0; i < 10; ++i) {
    int id2 = tid + i * 256;
    int row = id2 / 75, f4 = id2 - row * 75;
    ldsoff[i] = row * ROWB + SWZ(row, f4 * 8);
    sirow[i]  = row * NT;
    foff[i]   = f4 * 4;
  }
  int hoff[16];
  #pragma unroll
  for (int i = 0; i < 16; ++i) {
    int id2 = tid + i * 256;
    int row = id2 >> 7, c8 = id2 & 127;
    hoff[i] = row * ROWB + SWZ(row, 640 + c8 * 8);
  }

  int lenn[2];
  lenn[0] = lenp[b0 + (l & 15)];
  lenn[1] = lenp[b0 + 16 + (l & 15)];
  float bia[2][4];
  #pragma unroll
  for (int mf2 = 0; mf2 < 2; ++mf2) {
    int du = w * 8 + mf2 * 4 + (l >> 4);
    #pragma unroll
    for (int g = 0; g < 4; ++g) bia[mf2][g] = bv[g * 512 + u0 + du];
  }
  float cst[2][2] = {{0.f, 0.f}, {0.f, 0.f}};
  float hst[2][2] = {{0.f, 0.f}, {0.f, 0.f}};
  __syncthreads();

  // prologue: stage x(0), prefetch x(1)
  float4 px[10];
  #pragma unroll
  for (int i = 0; i < 10; ++i)
    if (i < 9 || tid < 96) {
      int eid = sI[sirow[i]];
      float4 xv = *(const float4*)(emb + eid * 300 + foff[i]);
      u64 pk = (u64)f2bf(xv.x) | ((u64)f2bf(xv.y) << 16) |
               ((u64)f2bf(xv.z) << 32) | ((u64)f2bf(xv.w) << 48);
      *(u64*)(sB + ldsoff[i]) = pk;
    }
  #pragma unroll
  for (int i = 0; i < 10; ++i)
    if (i < 9 || tid < 96) {
      int eid = sI[sirow[i] + 1];
      px[i] = *(const float4*)(emb + eid * 300 + foff[i]);
    }
  __syncthreads();

  const int r0 = l & 15, r1 = 16 + (l & 15);

  // x-GEMM(0): kt 0..9 (k < 320 region, x + zero pad)
  f32x4 xacc[2][2];
  xacc[0][0] = {0.f,0.f,0.f,0.f}; xacc[0][1] = {0.f,0.f,0.f,0.f};
  xacc[1][0] = {0.f,0.f,0.f,0.f}; xacc[1][1] = {0.f,0.f,0.f,0.f};
  #pragma unroll
  for (int kt = 0; kt < 10; ++kt) {
    int kb = kt * 64 + ((l >> 4) << 4);
    bf16x8 B0 = __builtin_bit_cast(bf16x8, *(const u32x4*)(sB + r0 * ROWB + SWZ(r0, kb)));
    bf16x8 B1 = __builtin_bit_cast(bf16x8, *(const u32x4*)(sB + r1 * ROWB + SWZ(r1, kb)));
    xacc[0][0] = __builtin_amdgcn_mfma_f32_16x16x32_bf16(A0[kt], B0, xacc[0][0], 0, 0, 0);
    xacc[0][1] = __builtin_amdgcn_mfma_f32_16x16x32_bf16(A0[kt], B1, xacc[0][1], 0, 0, 0);
    xacc[1][0] = __builtin_amdgcn_mfma_f32_16x16x32_bf16(A1[kt], B0, xacc[1][0], 0, 0, 0);
    xacc[1][1] = __builtin_amdgcn_mfma_f32_16x16x32_bf16(A1[kt], B1, xacc[1][1], 0, 0, 0);
  }

  for (int t = 0; t < NT; ++t) {
    if (t > 0) {
      const u64* hsrc = hbuf + (((lstm * 2 + ((t & 1) ^ 1)) * 256) + b0) * 128;
      u64 hld[16];
      bool need_bar = false;
      if (uni) {
        // bounded poll of 16 producer flags (one L2 line); fallback to L3 ctr
        const unsigned int* fl = flagb + ((grp * 2 + ((t & 1) ^ 1)) * 16);
        unsigned fv;
        bool ok;
        int iters = 0;
        do {
          asm volatile("global_load_dword %0, %1, off sc0\n\ts_waitcnt vmcnt(0)"
                       : "=&v"(fv) : "v"(fl + (l & 15)) : "memory");
          ok = __all(fv >= (unsigned)t);
          if (!ok) { __builtin_amdgcn_s_sleep(1); ++iters; }
        } while (!ok && iters < 4096);
        if (!ok) {
          // backstop: L3 counter (producers always bump it)
          unsigned target = 16u * (unsigned)t;
          while (__hip_atomic_load(blp, __ATOMIC_RELAXED, __HIP_MEMORY_SCOPE_AGENT) < target)
            __builtin_amdgcn_s_sleep(1);
        }
        SCHED0;
        // h(t-1) loads from XCD-local L2 (sc0 = L1-bypass)
        #pragma unroll
        for (int i = 0; i < 16; ++i) {
          u64 v;
          asm volatile("global_load_dwordx2 %0, %1, off sc0"
                       : "=&v"(v) : "v"(hsrc + tid + i * 256));
          hld[i] = v;
        }
        VM0;
      } else {
        if (tid == 0) {
          unsigned target = 16u * (unsigned)t;
          while (__hip_atomic_load(blp, __ATOMIC_RELAXED, __HIP_MEMORY_SCOPE_AGENT) < target)
            __builtin_amdgcn_s_sleep(1);
        }
        need_bar = true;
        #pragma unroll
        for (int i = 0; i < 16; ++i)
          hld[i] = __hip_atomic_load(&hsrc[tid + i * 256], __ATOMIC_RELAXED,
                                     __HIP_MEMORY_SCOPE_AGENT);
      }
      if (need_bar) { BAR(); SCHED0; }
      #pragma unroll
      for (int i = 0; i < 16; ++i) *(u64*)(sB + hoff[i]) = hld[i];
      LGKM0; BAR(); SCHED0;
      // h-GEMM: kt 10..25 (k in [320,832)), accumulate into xacc
      #pragma unroll
      for (int kt = 10; kt < 26; ++kt) {
        int kb = kt * 64 + ((l >> 4) << 4);
        bf16x8 B0 = __builtin_bit_cast(bf16x8, *(const u32x4*)(sB + r0 * ROWB + SWZ(r0, kb)));
        bf16x8 B1 = __builtin_bit_cast(bf16x8, *(const u32x4*)(sB + r1 * ROWB + SWZ(r1, kb)));
        xacc[0][0] = __builtin_amdgcn_mfma_f32_16x16x32_bf16(A0[kt], B0, xacc[0][0], 0, 0, 0);
        xacc[0][1] = __builtin_amdgcn_mfma_f32_16x16x32_bf16(A0[kt], B1, xacc[0][1], 0, 0, 0);
        xacc[1][0] = __builtin_amdgcn_mfma_f32_16x16x32_bf16(A1[kt], B0, xacc[1][0], 0, 0, 0);
        xacc[1][1] = __builtin_amdgcn_mfma_f32_16x16x32_bf16(A1[kt], B1, xacc[1][1], 0, 0, 0);
      }
    }

    // gates (acc reg r == gate r for cell (b,u): i,j,f,o)
    #pragma unroll
    for (int mf2 = 0; mf2 < 2; ++mf2)
      #pragma unroll
      for (int n = 0; n < 2; ++n) {
        f32x4 z = xacc[mf2][n];
        float zi = z[0] + bia[mf2][0];
        float zj = z[1] + bia[mf2][1];
        float zf = z[2] + bia[mf2][2];
        float zo = z[3] + bia[mf2][3];
        float cn = cst[mf2][n] * sigf(zf + 1.f) + sigf(zi) * tanhf_(zj);
        float hn = tanhf_(cn) * sigf(zo);
        if (t < lenn[n]) { cst[mf2][n] = cn; hst[mf2][n] = hn; }
        sH[n * 16 + (l & 15)][w * 8 + mf2 * 4 + (l >> 4)] = f2bf(hst[mf2][n]);
      }
    LGKM0; BAR(); SCHED0;

    // pack + h(t) store (uni: plain store -> XCD L2; else agent -> L3)
    {
      int bbL = tid >> 3, u8 = tid & 7;
      u64 pk = *(const u64*)&sH[bbL][u8 * 4];
      u64* hdst = hbuf + (((lstm * 2 + (t & 1)) * 256) + b0 + bbL) * 128 + (u0 >> 2) + u8;
      if (uni) *hdst = pk;
      else __hip_atomic_store(hdst, pk, __ATOMIC_RELAXED, __HIP_MEMORY_SCOPE_AGENT);
    }
    // stage x(t+1) from px regs into LDS (hides under store-ack)
    #pragma unroll
    for (int i = 0; i < 10; ++i)
      if (i < 9 || tid < 96) {
        float4 xv = px[i];
        u64 pk = (u64)f2bf(xv.x) | ((u64)f2bf(xv.y) << 16) |
                 ((u64)f2bf(xv.z) << 32) | ((u64)f2bf(xv.w) << 48);
        *(u64*)(sB + ldsoff[i]) = pk;
      }
    VM0; LGKM0; BAR();   // all waves' h stores committed before signaling

    // signal step completion: L2 flag (uni) + L3 counter (always)
    if (tid == 0) {
      if (uni)
        *(volatile unsigned int*)&flagb[(grp * 2 + (t & 1)) * 16 + ct] = (unsigned)(t + 1);
      __hip_atomic_fetch_add(blp, 1u, __ATOMIC_RELAXED, __HIP_MEMORY_SCOPE_AGENT);
    }
    SCHED0;

    // prefetch x(t+2) (consumed next tail -> latency fully hidden)
    {
      int tn2 = (t + 2) & (NT - 1);
      #pragma unroll
      for (int i = 0; i < 10; ++i)
        if (i < 9 || tid < 96) {
          int eid = sI[sirow[i] + tn2];
          px[i] = *(const float4*)(emb + eid * 300 + foff[i]);
        }
    }
    // x-GEMM(t+1): kt 0..9 into fresh xacc (in the barrier-skew shadow)
    xacc[0][0] = {0.f,0.f,0.f,0.f}; xacc[0][1] = {0.f,0.f,0.f,0.f};
    xacc[1][0] = {0.f,0.f,0.f,0.f}; xacc[1][1] = {0.f,0.f,0.f,0.f};
    #pragma unroll
    for (int kt = 0; kt < 10; ++kt) {
      int kb = kt * 64 + ((l >> 4) << 4);
      bf16x8 B0 = __builtin_bit_cast(bf16x8, *(const u32x4*)(sB + r0 * ROWB + SWZ(r0, kb)));
      bf16x8 B1 = __builtin_bit_cast(bf16x8, *(const u32x4*)(sB + r1 * ROWB + SWZ(r1, kb)));
      xacc[0][0] = __builtin_amdgcn_mfma_f32_16x16x32_bf16(A0[kt], B0, xacc[0][0], 0, 0, 0);
      xacc[0][1] = __builtin_amdgcn_mfma_f32_16x16x32_bf16(A0[kt], B1, xacc[0][1], 0, 0, 0);
      xacc[1][0] = __builtin_amdgcn_mfma_f32_16x16x32_bf16(A1[kt], B0, xacc[1][0], 0, 0, 0);
      xacc[1][1] = __builtin_amdgcn_mfma_f32_16x16x32_bf16(A1[kt], B1, xacc[1][1], 0, 0, 0);
    }
  }

  #pragma unroll
  for (int mf2 = 0; mf2 < 2; ++mf2)
    #pragma unroll
    for (int n = 0; n < 2; ++n) {
      int bb = b0 + n * 16 + (l & 15);
      int uu = u0 + w * 8 + mf2 * 4 + (l >> 4);
      hfin[lstm * (256 * 512) + bb * 512 + uu] = hst[mf2][n];
    }
}

__global__ void dense_out(const float* __restrict__ hfin,
                          const float* __restrict__ Wd, const float* __restrict__ bd,
                          float* __restrict__ out) {
  const int b = blockIdx.x, l = threadIdx.x;
  float a0 = 0.f, a1 = 0.f, a2 = 0.f;
  for (int i = l; i < 1024; i += 64) {
    float hv = (i < 512) ? hfin[b * 512 + i] : hfin[256 * 512 + b * 512 + (i - 512)];
    a0 += hv * Wd[i * 3 + 0];
    a1 += hv * Wd[i * 3 + 1];
    a2 += hv * Wd[i * 3 + 2];
  }
  #pragma unroll
  for (int off = 32; off > 0; off >>= 1) {
    a0 += __shfl_down(a0, off);
    a1 += __shfl_down(a1, off);
    a2 += __shfl_down(a2, off);
  }
  if (l == 0) {
    out[b * 3 + 0] = a0 + bd[0];
    out[b * 3 + 1] = a1 + bd[1];
    out[b * 3 + 2] = a2 + bd[2];
  }
}

extern "C" void kernel_launch(void* const* d_in, const int* in_sizes, int n_in,
                              void* d_out, int out_size, void* d_ws, size_t ws_size,
                              hipStream_t stream) {
  const int*   lids = (const int*)d_in[0];
  const int*   rids = (const int*)d_in[1];
  const int*   llen = (const int*)d_in[2];
  const int*   rlen = (const int*)d_in[3];
  const float* emb  = (const float*)d_in[4];
  const float* Wl   = (const float*)d_in[5];
  const float* bl   = (const float*)d_in[6];
  const float* Wr   = (const float*)d_in[7];
  const float* br   = (const float*)d_in[8];
  const float* Wd   = (const float*)d_in[9];
  const float* bd   = (const float*)d_in[10];

  unsigned char* ws = (unsigned char*)d_ws;
  unsigned int* bar = (unsigned int*)ws;             // 8 KiB sync area
  u64*   hbuf = (u64*)(ws + 8192);                   // 1 MiB
  float* hfin = (float*)(ws + 8192 + (1u << 20));    // 1 MiB

  hipMemsetAsync(bar, 0, 8192, stream);              // re-arm handshake/ctrs/flags
  hipLaunchKernelGGL(lstm_persist, dim3(256), dim3(256), 0, stream,
                     lids, rids, llen, rlen, emb, Wl, bl, Wr, br, hbuf, hfin, bar);
  hipLaunchKernelGGL(dense_out, dim3(256), dim3(64), 0, stream,
                     hfin, Wd, bd, (float*)d_out);
}

// Round 9
// 681.582 us; speedup vs baseline: 30.1066x; 30.1066x over previous
//
#include <hip/hip_runtime.h>

// TdLstm: twin BasicLSTM (i,j,f,o; forget_bias=1) + final dense.
// Persistent kernel, 256 WGs, LDS ~70.5KB (proven residency size).
// W^T in VGPRs (52 frags/wave, M-split). XCD handshake (proven r8) builds
// 16-WG groups from co-located WGs; h exchange via XCD-local L2 (plain
// stores + sc0 streamed loads — proven coherent r8). Step detection via
// L3 agent-atomic group counter (proven r3/4/6; sc0-POLLING is stale, r8).
// ws: [0,8192) handshake/counters (memset), [8192,+1MiB) h ping-pong,
// then 1MiB final h (f32).

using bf16x8 = __attribute__((ext_vector_type(8))) __bf16;
using f32x4  = __attribute__((ext_vector_type(4))) float;
using u32x4  = __attribute__((ext_vector_type(4))) unsigned int;
typedef unsigned short u16;
typedef unsigned long long u64;

#define NT 128
#define ROWB 1664                                  // 832 k-elems * 2B per B-row
#define SWZ(row, off) ((off) ^ (((row) & 7) << 4)) // bank swizzle, 16B granules

#define LGKM0  asm volatile("s_waitcnt lgkmcnt(0)" ::: "memory")
#define VM0    asm volatile("s_waitcnt vmcnt(0)" ::: "memory")
#define BAR()  __builtin_amdgcn_s_barrier()
#define SCHED0 __builtin_amdgcn_sched_barrier(0)

__device__ __forceinline__ u16 f2bf(float f) {
  union { float f; unsigned u; } v; v.f = f;
  unsigned r = v.u + 0x7fffu + ((v.u >> 16) & 1u);
  return (u16)(r >> 16);
}
__device__ __forceinline__ float sigf(float x) { return 1.f / (1.f + __expf(-x)); }
__device__ __forceinline__ float tanhf_(float x) { return 2.f / (1.f + __expf(-2.f * x)) - 1.f; }

// static-index store into A-fragment array (avoid scratch, rule #20)
__device__ __forceinline__ void setA26(bf16x8 (&A)[26], int kt, bf16x8 v) {
  switch (kt) {
    case 0:A[0]=v;break;  case 1:A[1]=v;break;  case 2:A[2]=v;break;
    case 3:A[3]=v;break;  case 4:A[4]=v;break;  case 5:A[5]=v;break;
    case 6:A[6]=v;break;  case 7:A[7]=v;break;  case 8:A[8]=v;break;
    case 9:A[9]=v;break;  case 10:A[10]=v;break; case 11:A[11]=v;break;
    case 12:A[12]=v;break; case 13:A[13]=v;break; case 14:A[14]=v;break;
    case 15:A[15]=v;break; case 16:A[16]=v;break; case 17:A[17]=v;break;
    case 18:A[18]=v;break; case 19:A[19]=v;break; case 20:A[20]=v;break;
    case 21:A[21]=v;break; case 22:A[22]=v;break; case 23:A[23]=v;break;
    case 24:A[24]=v;break; case 25:A[25]=v;break;
  }
}

__global__ __launch_bounds__(256, 1) void lstm_persist(
    const int* __restrict__ lids, const int* __restrict__ rids,
    const int* __restrict__ llen, const int* __restrict__ rlen,
    const float* __restrict__ emb,
    const float* __restrict__ Wl, const float* __restrict__ bl,
    const float* __restrict__ Wr, const float* __restrict__ br,
    u64* __restrict__ hbuf,      // [2 lstm][2 buf][256][128] u64 (bf16 x4)
    float* __restrict__ hfin,    // [2 lstm][256][512] f32
    unsigned int* __restrict__ bar) // 8KB: [0..511] grp ctrs, [512] grid, [576..831] xcd tab
{
  __shared__ __align__(16) unsigned char sB[32 * ROWB]; // 52 KiB (also W scratch)
  __shared__ __align__(8)  u16 sH[32][36];              // h-out staging
  __shared__ int sI[4096];                              // xcd table / ids (16 KiB)
  __shared__ int sCnt[8];

  const int tid = threadIdx.x;
  const int w = tid >> 6, l = tid & 63;
  const int bid = blockIdx.x;

  // ---- handshake: publish XCD, grid barrier (L3, proven), read placement ----
  unsigned myxcd;
  asm volatile("s_getreg_b32 %0, hwreg(20, 0, 32)" : "=s"(myxcd));  // HW_REG_XCC_ID
  myxcd &= 7u;
  if (tid == 0)
    __hip_atomic_store(&bar[576 + bid], myxcd, __ATOMIC_RELAXED, __HIP_MEMORY_SCOPE_AGENT);
  VM0;
  if (tid == 0) {
    __hip_atomic_fetch_add(&bar[512], 1u, __ATOMIC_RELAXED, __HIP_MEMORY_SCOPE_AGENT);
    while (__hip_atomic_load(&bar[512], __ATOMIC_RELAXED, __HIP_MEMORY_SCOPE_AGENT) < 256u)
      __builtin_amdgcn_s_sleep(8);
  }
  __syncthreads();
  if (tid < 256)
    sI[tid] = (int)__hip_atomic_load(&bar[576 + tid], __ATOMIC_RELAXED, __HIP_MEMORY_SCOPE_AGENT);
  __syncthreads();
  if (tid < 8) {
    int c = 0;
    for (int i = 0; i < 256; ++i) c += (sI[i] == tid);
    sCnt[tid] = c;
  }
  __syncthreads();
  bool uni = true;
  #pragma unroll
  for (int x = 0; x < 8; ++x) uni &= (sCnt[x] == 32);
  int rank = 0;
  for (int i = 0; i < bid; ++i) rank += (sI[i] == (int)myxcd);
  __syncthreads();

  // ---- role assignment (bijective either way -> placement-independent output)
  int grp, ct;
  if (uni) { grp = (int)myxcd * 2 + (rank >> 4); ct = rank & 15; }
  else     { int xcd = bid & 7, idxq = bid >> 3; grp = xcd * 2 + (idxq >> 4); ct = idxq & 15; }
  const int lstm = grp >> 3, bt = grp & 7;
  const int b0 = bt * 32, u0 = ct * 32;

  const int*   ids  = lstm ? rids : lids;
  const int*   lenp = lstm ? rlen : llen;
  const float* W    = lstm ? Wr : Wl;
  const float* bv   = lstm ? br : bl;
  unsigned int* const blp = bar + grp * 32;     // L3 agent counter (both modes)

  // ---- one-time: build W^T A-fragments (M-split: wave w owns mf=2w,2w+1) ----
  bf16x8 A0[26], A1[26];
  {
    float* sW = (float*)sB;                // [4 g][64 r][32 c] = 32 KiB scratch
    for (int kc = 0; kc < 13; ++kc) {
      for (int i = 0; i < 32; ++i) {
        int id2 = tid + i * 256;
        int c = id2 & 31, r = (id2 >> 5) & 63, g = id2 >> 11;
        int kk = kc * 64 + r;
        float v = 0.f;
        if (kk < 300)       v = W[kk * 2048 + g * 512 + u0 + c];
        else if (kk >= 320) v = W[(kk - 20) * 2048 + g * 512 + u0 + c];
        sW[(g * 64 + r) * 32 + c] = v;
      }
      __syncthreads();
      #pragma unroll
      for (int kt2 = 0; kt2 < 2; ++kt2) {
        int kt = kc * 2 + kt2;
        #pragma unroll
        for (int mf2 = 0; mf2 < 2; ++mf2) {
          int mf = w * 2 + mf2;
          int rho = mf * 16 + (l & 15);    // col map rho = du*4 + g
          int du = rho >> 2, g = rho & 3;
          union { u16 s[8]; bf16x8 v; } tmp;
          #pragma unroll
          for (int j = 0; j < 8; ++j) {
            int kr = kt2 * 32 + ((l >> 4) << 3) + j;
            tmp.s[j] = f2bf(sW[(g * 64 + kr) * 32 + du]);
          }
          if (mf2 == 0) setA26(A0, kt, tmp.v); else setA26(A1, kt, tmp.v);
        }
      }
      __syncthreads();
    }
  }

  // zero-pad x region k in [300,320)
  if (tid < 160) {
    int row = tid / 5, c5 = tid - (tid / 5) * 5;
    *(u64*)(sB + row * ROWB + SWZ(row, 600 + c5 * 8)) = 0ULL;
  }
  // preload ids for this b-tile
  {
    const int* src = ids + b0 * NT;
    #pragma unroll
    for (int i = 0; i < 4; ++i)
      *(int4*)&sI[(tid + i * 256) * 4] = *(const int4*)&src[(tid + i * 256) * 4];
  }

  int ldsoff[10], sirow[10], foff[10];
  #pragma unroll
  for (int i = 0; i < 10; ++i) {
    int id2 = tid + i * 256;
    int row = id2 / 75, f4 = id2 - row * 75;
    ldsoff[i] = row * ROWB + SWZ(row, f4 * 8);
    sirow[i]  = row * NT;
    foff[i]   = f4 * 4;
  }
  int hoff[16];
  #pragma unroll
  for (int i = 0; i < 16; ++i) {
    int id2 = tid + i * 256;
    int row = id2 >> 7, c8 = id2 & 127;
    hoff[i] = row * ROWB + SWZ(row, 640 + c8 * 8);
  }

  int lenn[2];
  lenn[0] = lenp[b0 + (l & 15)];
  lenn[1] = lenp[b0 + 16 + (l & 15)];
  float bia[2][4];
  #pragma unroll
  for (int mf2 = 0; mf2 < 2; ++mf2) {
    int du = w * 8 + mf2 * 4 + (l >> 4);
    #pragma unroll
    for (int g = 0; g < 4; ++g) bia[mf2][g] = bv[g * 512 + u0 + du];
  }
  float cst[2][2] = {{0.f, 0.f}, {0.f, 0.f}};
  float hst[2][2] = {{0.f, 0.f}, {0.f, 0.f}};
  __syncthreads();

  // prologue: stage x(0), prefetch x(1)
  float4 px[10];
  #pragma unroll
  for (int i = 0; i < 10; ++i)
    if (i < 9 || tid < 96) {
      int eid = sI[sirow[i]];
      float4 xv = *(const float4*)(emb + eid * 300 + foff[i]);
      u64 pk = (u64)f2bf(xv.x) | ((u64)f2bf(xv.y) << 16) |
               ((u64)f2bf(xv.z) << 32) | ((u64)f2bf(xv.w) << 48);
      *(u64*)(sB + ldsoff[i]) = pk;
    }
  #pragma unroll
  for (int i = 0; i < 10; ++i)
    if (i < 9 || tid < 96) {
      int eid = sI[sirow[i] + 1];
      px[i] = *(const float4*)(emb + eid * 300 + foff[i]);
    }
  __syncthreads();

  const int r0 = l & 15, r1 = 16 + (l & 15);

  // x-GEMM(0): kt 0..9 (k < 320 region, x + zero pad)
  f32x4 xacc[2][2];
  xacc[0][0] = {0.f,0.f,0.f,0.f}; xacc[0][1] = {0.f,0.f,0.f,0.f};
  xacc[1][0] = {0.f,0.f,0.f,0.f}; xacc[1][1] = {0.f,0.f,0.f,0.f};
  #pragma unroll
  for (int kt = 0; kt < 10; ++kt) {
    int kb = kt * 64 + ((l >> 4) << 4);
    bf16x8 B0 = __builtin_bit_cast(bf16x8, *(const u32x4*)(sB + r0 * ROWB + SWZ(r0, kb)));
    bf16x8 B1 = __builtin_bit_cast(bf16x8, *(const u32x4*)(sB + r1 * ROWB + SWZ(r1, kb)));
    xacc[0][0] = __builtin_amdgcn_mfma_f32_16x16x32_bf16(A0[kt], B0, xacc[0][0], 0, 0, 0);
    xacc[0][1] = __builtin_amdgcn_mfma_f32_16x16x32_bf16(A0[kt], B1, xacc[0][1], 0, 0, 0);
    xacc[1][0] = __builtin_amdgcn_mfma_f32_16x16x32_bf16(A1[kt], B0, xacc[1][0], 0, 0, 0);
    xacc[1][1] = __builtin_amdgcn_mfma_f32_16x16x32_bf16(A1[kt], B1, xacc[1][1], 0, 0, 0);
  }

  for (int t = 0; t < NT; ++t) {
    if (t > 0) {
      // detect: L3 agent counter (proven protocol; sc0-polling is stale, r8)
      if (tid == 0) {
        unsigned target = 16u * (unsigned)t;
        while (__hip_atomic_load(blp, __ATOMIC_RELAXED, __HIP_MEMORY_SCOPE_AGENT) < target)
          __builtin_amdgcn_s_sleep(1);
      }
      BAR(); SCHED0;
      // h(t-1) loads: uni -> sc0 streamed loads from XCD-local L2
      const u64* hsrc = hbuf + (((lstm * 2 + ((t & 1) ^ 1)) * 256) + b0) * 128;
      u64 hld[16];
      if (uni) {
        #pragma unroll
        for (int i = 0; i < 16; ++i) {
          u64 v;
          asm volatile("global_load_dwordx2 %0, %1, off sc0"
                       : "=&v"(v) : "v"(hsrc + tid + i * 256));
          hld[i] = v;
        }
        VM0;
      } else {
        #pragma unroll
        for (int i = 0; i < 16; ++i)
          hld[i] = __hip_atomic_load(&hsrc[tid + i * 256], __ATOMIC_RELAXED,
                                     __HIP_MEMORY_SCOPE_AGENT);
      }
      #pragma unroll
      for (int i = 0; i < 16; ++i) *(u64*)(sB + hoff[i]) = hld[i];
      LGKM0; BAR(); SCHED0;
      // h-GEMM: kt 10..25 (k in [320,832)), accumulate into xacc
      #pragma unroll
      for (int kt = 10; kt < 26; ++kt) {
        int kb = kt * 64 + ((l >> 4) << 4);
        bf16x8 B0 = __builtin_bit_cast(bf16x8, *(const u32x4*)(sB + r0 * ROWB + SWZ(r0, kb)));
        bf16x8 B1 = __builtin_bit_cast(bf16x8, *(const u32x4*)(sB + r1 * ROWB + SWZ(r1, kb)));
        xacc[0][0] = __builtin_amdgcn_mfma_f32_16x16x32_bf16(A0[kt], B0, xacc[0][0], 0, 0, 0);
        xacc[0][1] = __builtin_amdgcn_mfma_f32_16x16x32_bf16(A0[kt], B1, xacc[0][1], 0, 0, 0);
        xacc[1][0] = __builtin_amdgcn_mfma_f32_16x16x32_bf16(A1[kt], B0, xacc[1][0], 0, 0, 0);
        xacc[1][1] = __builtin_amdgcn_mfma_f32_16x16x32_bf16(A1[kt], B1, xacc[1][1], 0, 0, 0);
      }
    }

    // gates (acc reg r == gate r for cell (b,u): i,j,f,o)
    #pragma unroll
    for (int mf2 = 0; mf2 < 2; ++mf2)
      #pragma unroll
      for (int n = 0; n < 2; ++n) {
        f32x4 z = xacc[mf2][n];
        float zi = z[0] + bia[mf2][0];
        float zj = z[1] + bia[mf2][1];
        float zf = z[2] + bia[mf2][2];
        float zo = z[3] + bia[mf2][3];
        float cn = cst[mf2][n] * sigf(zf + 1.f) + sigf(zi) * tanhf_(zj);
        float hn = tanhf_(cn) * sigf(zo);
        if (t < lenn[n]) { cst[mf2][n] = cn; hst[mf2][n] = hn; }
        sH[n * 16 + (l & 15)][w * 8 + mf2 * 4 + (l >> 4)] = f2bf(hst[mf2][n]);
      }
    LGKM0; BAR(); SCHED0;

    // pack + h(t) store (uni: plain store -> XCD L2; else agent -> L3)
    {
      int bbL = tid >> 3, u8 = tid & 7;
      u64 pk = *(const u64*)&sH[bbL][u8 * 4];
      u64* hdst = hbuf + (((lstm * 2 + (t & 1)) * 256) + b0 + bbL) * 128 + (u0 >> 2) + u8;
      if (uni) *hdst = pk;
      else __hip_atomic_store(hdst, pk, __ATOMIC_RELAXED, __HIP_MEMORY_SCOPE_AGENT);
    }
    // stage x(t+1) from px regs into LDS (hides under store-ack)
    #pragma unroll
    for (int i = 0; i < 10; ++i)
      if (i < 9 || tid < 96) {
        float4 xv = px[i];
        u64 pk = (u64)f2bf(xv.x) | ((u64)f2bf(xv.y) << 16) |
                 ((u64)f2bf(xv.z) << 32) | ((u64)f2bf(xv.w) << 48);
        *(u64*)(sB + ldsoff[i]) = pk;
      }
    VM0; LGKM0; BAR();   // h committed to L2/L3 before signaling

    // arrive: L3 agent counter (both modes)
    if (tid == 0)
      __hip_atomic_fetch_add(blp, 1u, __ATOMIC_RELAXED, __HIP_MEMORY_SCOPE_AGENT);
    SCHED0;

    // prefetch x(t+2) (consumed next tail -> latency fully hidden)
    {
      int tn2 = (t + 2) & (NT - 1);
      #pragma unroll
      for (int i = 0; i < 10; ++i)
        if (i < 9 || tid < 96) {
          int eid = sI[sirow[i] + tn2];
          px[i] = *(const float4*)(emb + eid * 300 + foff[i]);
        }
    }
    // x-GEMM(t+1): kt 0..9 into fresh xacc (in the barrier-skew shadow)
    xacc[0][0] = {0.f,0.f,0.f,0.f}; xacc[0][1] = {0.f,0.f,0.f,0.f};
    xacc[1][0] = {0.f,0.f,0.f,0.f}; xacc[1][1] = {0.f,0.f,0.f,0.f};
    #pragma unroll
    for (int kt = 0; kt < 10; ++kt) {
      int kb = kt * 64 + ((l >> 4) << 4);
      bf16x8 B0 = __builtin_bit_cast(bf16x8, *(const u32x4*)(sB + r0 * ROWB + SWZ(r0, kb)));
      bf16x8 B1 = __builtin_bit_cast(bf16x8, *(const u32x4*)(sB + r1 * ROWB + SWZ(r1, kb)));
      xacc[0][0] = __builtin_amdgcn_mfma_f32_16x16x32_bf16(A0[kt], B0, xacc[0][0], 0, 0, 0);
      xacc[0][1] = __builtin_amdgcn_mfma_f32_16x16x32_bf16(A0[kt], B1, xacc[0][1], 0, 0, 0);
      xacc[1][0] = __builtin_amdgcn_mfma_f32_16x16x32_bf16(A1[kt], B0, xacc[1][0], 0, 0, 0);
      xacc[1][1] = __builtin_amdgcn_mfma_f32_16x16x32_bf16(A1[kt], B1, xacc[1][1], 0, 0, 0);
    }
  }

  #pragma unroll
  for (int mf2 = 0; mf2 < 2; ++mf2)
    #pragma unroll
    for (int n = 0; n < 2; ++n) {
      int bb = b0 + n * 16 + (l & 15);
      int uu = u0 + w * 8 + mf2 * 4 + (l >> 4);
      hfin[lstm * (256 * 512) + bb * 512 + uu] = hst[mf2][n];
    }
}

__global__ void dense_out(const float* __restrict__ hfin,
                          const float* __restrict__ Wd, const float* __restrict__ bd,
                          float* __restrict__ out) {
  const int b = blockIdx.x, l = threadIdx.x;
  float a0 = 0.f, a1 = 0.f, a2 = 0.f;
  for (int i = l; i < 1024; i += 64) {
    float hv = (i < 512) ? hfin[b * 512 + i] : hfin[256 * 512 + b * 512 + (i - 512)];
    a0 += hv * Wd[i * 3 + 0];
    a1 += hv * Wd[i * 3 + 1];
    a2 += hv * Wd[i * 3 + 2];
  }
  #pragma unroll
  for (int off = 32; off > 0; off >>= 1) {
    a0 += __shfl_down(a0, off);
    a1 += __shfl_down(a1, off);
    a2 += __shfl_down(a2, off);
  }
  if (l == 0) {
    out[b * 3 + 0] = a0 + bd[0];
    out[b * 3 + 1] = a1 + bd[1];
    out[b * 3 + 2] = a2 + bd[2];
  }
}

extern "C" void kernel_launch(void* const* d_in, const int* in_sizes, int n_in,
                              void* d_out, int out_size, void* d_ws, size_t ws_size,
                              hipStream_t stream) {
  const int*   lids = (const int*)d_in[0];
  const int*   rids = (const int*)d_in[1];
  const int*   llen = (const int*)d_in[2];
  const int*   rlen = (const int*)d_in[3];
  const float* emb  = (const float*)d_in[4];
  const float* Wl   = (const float*)d_in[5];
  const float* bl   = (const float*)d_in[6];
  const float* Wr   = (const float*)d_in[7];
  const float* br   = (const float*)d_in[8];
  const float* Wd   = (const float*)d_in[9];
  const float* bd   = (const float*)d_in[10];

  unsigned char* ws = (unsigned char*)d_ws;
  unsigned int* bar = (unsigned int*)ws;             // 8 KiB sync area
  u64*   hbuf = (u64*)(ws + 8192);                   // 1 MiB
  float* hfin = (float*)(ws + 8192 + (1u << 20));    // 1 MiB

  hipMemsetAsync(bar, 0, 8192, stream);              // re-arm handshake/counters
  hipLaunchKernelGGL(lstm_persist, dim3(256), dim3(256), 0, stream,
                     lids, rids, llen, rlen, emb, Wl, bl, Wr, br, hbuf, hfin, bar);
  hipLaunchKernelGGL(dense_out, dim3(256), dim3(64), 0, stream,
                     hfin, Wd, bd, (float*)d_out);
}